// Round 1
// baseline (261.935 us; speedup 1.0000x reference)
//
#include <hip/hip_runtime.h>
#include <math.h>

// PositionEmbeddingSine, MI355X.
// Key insight: the reference's searchsorted+scatter is the identity map
// (b is sorted, max_len entries per batch), so out row m = expansion of
// coords row m. Pure streaming write of 251.7 MB -> memory-bound.
//
// Feature layout within a row (192 floats): f = d*64 + 2k + parity,
//   angle_k(d) = coord_d/(s_d-1+eps)*2pi * 10000^(-k/32)
//   f even -> sin(angle), f odd -> cos(angle), same angle for the pair.
// One thread per float4: [sin(a_k),cos(a_k),sin(a_{k+1}),cos(a_{k+1})].

__global__ __launch_bounds__(256) void pes_kernel(
    const int* __restrict__ coords,
    const int* __restrict__ psx, const int* __restrict__ psy, const int* __restrict__ psz,
    float4* __restrict__ out, int M)
{
    const int tid = blockIdx.x * blockDim.x + threadIdx.x;
    const int total = M * 48;            // 48 float4s per row of 192 floats
    if (tid >= total) return;

    const int m   = tid / 48;
    const int q   = tid - m * 48;        // 0..47
    const int d   = q >> 4;              // 0..2  (x,y,z)
    const int p16 = q & 15;              // 0..15 -> k0 = 2*p16
    const int k0  = p16 << 1;

    const int s = (d == 0) ? *psx : ((d == 1) ? *psy : *psz);
    const float denom = (float)(s - 1) + 1e-6f;
    const float scale = 6.28318530717958647692f / denom;   // 2*pi / denom

    const int   v    = coords[(m << 2) + 1 + d];
    const float base = (float)v * scale;

    // inv_dt(k) = 10000^(-k/32) = exp2(-k * log2(10000)/32)
    const float K = 0.41524101186092029f;   // log2(10000)/32
    const float a0 = base * __builtin_amdgcn_exp2f(-(float)k0 * K);
    const float a1 = base * __builtin_amdgcn_exp2f(-(float)(k0 + 1) * K);

    // args are in [0, 2*pi]; HW sin/cos precision (~1e-6 here) is far
    // inside the 2e-2 tolerance.
    float4 r;
    r.x = __sinf(a0);
    r.y = __cosf(a0);
    r.z = __sinf(a1);
    r.w = __cosf(a1);
    out[tid] = r;
}

extern "C" void kernel_launch(void* const* d_in, const int* in_sizes, int n_in,
                              void* d_out, int out_size, void* d_ws, size_t ws_size,
                              hipStream_t stream) {
    const int* coords = (const int*)d_in[0];
    const int* psx    = (const int*)d_in[1];
    const int* psy    = (const int*)d_in[2];
    const int* psz    = (const int*)d_in[3];
    // d_in[4] (n_batches) and d_in[5] (max_len) are not needed: the scatter
    // is the identity map (see header comment).

    const int M     = in_sizes[0] / 4;   // coords is (M,4)
    const int total = M * 48;
    const int block = 256;
    const int grid  = (total + block - 1) / block;

    pes_kernel<<<grid, block, 0, stream>>>(coords, psx, psy, psz, (float4*)d_out, M);
}

// Round 3
// 261.792 us; speedup vs baseline: 1.0005x; 1.0005x over previous
//
#include <hip/hip_runtime.h>
#include <math.h>

// PositionEmbeddingSine, MI355X.
// The reference's searchsorted+scatter is the identity map (b sorted,
// max_len rows per batch), so out row m = sine/cosine expansion of coords
// row m. Pure streaming write of 251.7 MB -> memory-bound, floor ~41 us.
//
// Mapping: one thread per (row m, k-pair kp), kp in [0,16). Thread loads
// the whole coord row as int4, computes the two shared inv_dt factors
// (k0=2kp, k0+1), then writes three float4s (one per spatial dim d) at
// feature offsets d*64 + 4*kp:
//   [sin(a_k0), cos(a_k0), sin(a_k0+1), cos(a_k0+1)],  a = v_d*scale_d*inv_dt
// No integer division anywhere; coords fetched once per row via dwordx4.
// Stores use native ext_vector float4 (nontemporal builtin rejects
// HIP_vector_type).

typedef float  vfloat4 __attribute__((ext_vector_type(4)));
typedef int    vint4   __attribute__((ext_vector_type(4)));

__global__ __launch_bounds__(256) void pes_kernel(
    const vint4* __restrict__ coords,
    const int* __restrict__ psx, const int* __restrict__ psy, const int* __restrict__ psz,
    vfloat4* __restrict__ out, int M)
{
    const int tid = blockIdx.x * blockDim.x + threadIdx.x;
    if (tid >= M * 16) return;

    const int m  = tid >> 4;
    const int kp = tid & 15;          // k-pair index, k0 = 2*kp

    const vint4 c = coords[m];        // [b, x, y, z] — one dwordx4

    const float TWO_PI = 6.28318530717958647692f;
    const float scx = TWO_PI / ((float)(*psx - 1) + 1e-6f);
    const float scy = TWO_PI / ((float)(*psy - 1) + 1e-6f);
    const float scz = TWO_PI / ((float)(*psz - 1) + 1e-6f);

    // inv_dt(k) = 10000^(-k/32) = exp2(-k * log2(10000)/32)
    const float K  = 0.41524101186092029f;        // log2(10000)/32
    const float k0 = (float)(kp << 1);
    const float inv0 = __builtin_amdgcn_exp2f(-k0 * K);
    const float inv1 = __builtin_amdgcn_exp2f(-(k0 + 1.0f) * K);

    const float bx = (float)c.y * scx;
    const float by = (float)c.z * scy;
    const float bz = (float)c.w * scz;

    vfloat4* row = out + m * 48 + kp; // 48 float4s per row of 192 floats

    vfloat4 r;
    float a0, a1;

    a0 = bx * inv0; a1 = bx * inv1;
    r.x = __sinf(a0); r.y = __cosf(a0); r.z = __sinf(a1); r.w = __cosf(a1);
    __builtin_nontemporal_store(r, row);           // d=0 block

    a0 = by * inv0; a1 = by * inv1;
    r.x = __sinf(a0); r.y = __cosf(a0); r.z = __sinf(a1); r.w = __cosf(a1);
    __builtin_nontemporal_store(r, row + 16);      // d=1 block

    a0 = bz * inv0; a1 = bz * inv1;
    r.x = __sinf(a0); r.y = __cosf(a0); r.z = __sinf(a1); r.w = __cosf(a1);
    __builtin_nontemporal_store(r, row + 32);      // d=2 block
}

extern "C" void kernel_launch(void* const* d_in, const int* in_sizes, int n_in,
                              void* d_out, int out_size, void* d_ws, size_t ws_size,
                              hipStream_t stream) {
    const vint4* coords = (const vint4*)d_in[0];
    const int* psx      = (const int*)d_in[1];
    const int* psy      = (const int*)d_in[2];
    const int* psz      = (const int*)d_in[3];
    // d_in[4]/d_in[5] (n_batches, max_len) unused: scatter is identity.

    const int M     = in_sizes[0] / 4;   // coords is (M,4)
    const int total = M * 16;            // one thread per (row, k-pair)
    const int block = 256;
    const int grid  = (total + block - 1) / block;

    pes_kernel<<<grid, block, 0, stream>>>(coords, psx, psy, psz, (vfloat4*)d_out, M);
}